// Round 1
// baseline (143.071 us; speedup 1.0000x reference)
//
#include <hip/hip_runtime.h>
#include <hip/hip_bf16.h>

#define NB 32
#define NS 4
#define NL 64
#define NC 32
#define NH 4
#define ND 8
#define NCP 16

using fp = const float* __restrict__;

// ---------------------------------------------------------------------------
// K1 v4: block=(b,s,half) -> 256 blocks, now 512 threads = 8 waves
// (2 waves/SIMD instead of 1 -> 2x latency hiding; per-thread chains halved).
// Phase 1 (w=t>>6 in [0,8), l=t&63): every thread embeds+LNs row l (dup x8),
//   computes a 4-wide QKV e-slice e in [4w,4w+4) -> qs/ks/vs [e][l];
//   xs_s written via static-index predicated loop.
// Phase 2: head h=w>>1; sub=((w&1)<<6)|l -> rl=sub>>2 (32 rows), q4=sub&3
//   (m-quarter, 16 m's per lane). Softmax/PV combined via shfl_xor 1 and 2.
//   Gate: all 8 channels computed (static o[] index), lanes q4==c8>>1 write.
// Phase 3: out-proj 2 channels/thread (r3=t&31, cg=t>>5 in [0,16)), LN via
//   LDS reduce over 16 channel-groups (red stride 17 = conflict-free).
// ---------------------------------------------------------------------------
__global__ __launch_bounds__(512) void k1_attn(
    fp ctcf, fp hac, fp me1, fp me3, fp bulk,
    fp we_w, fp we_b, fp pos, fp mn_g, fp mn_b,
    fp wq, fp bq, fp wk, fp bk, fp wv, fp bv,
    fp wo, fp bo, fp an_g, fp an_b,
    fp conv_w, fp conv_b, fp gate_w, fp gate_b,
    float* __restrict__ xpostT)
{
    __shared__ float qs_s[NC*NL];      // [e][l]
    __shared__ float ks_s[NC*NL];      // [e][l]
    __shared__ float vs_s[NC*NL];      // [e][l]
    __shared__ float xs_s[NC*NL];      // [e][l]
    __shared__ float ao_s[NC*NL];      // [e][r]
    __shared__ float bulk_s[32*65];    // [lr][m], rows of this half, padded
    __shared__ float red1[32*17], red2[32*17];   // stride 17: conflict-free
    __shared__ float mstat[32], istat[32];

    const int t    = threadIdx.x;
    const int w    = t >> 6;           // wave 0..7
    const int l    = t & 63;
    const int bx   = blockIdx.x;
    const int b    = bx >> 3;
    const int s    = (bx >> 1) & 3;
    const int half = bx & 1;

    // stage this half's 32 bulk rows (8.1 KB), padded
    for (int idx = t; idx < 32*NL; idx += 512){
        int lr = idx >> 6, m = idx & 63;
        bulk_s[lr*65 + m] = bulk[b*NL*NL + (half*32 + lr)*NL + m];
    }

    fp sigp = (s == 0) ? ctcf : (s == 1) ? hac : (s == 2) ? me1 : me3;
    const float sig = sigp[b*NL + l];

    // ---- phase 1: embed + LN + 4-wide QKV slice for row l ----
    float x[NC];
    float mean = 0.f;
#pragma unroll
    for (int c = 0; c < NC; c++){
        x[c] = sig * we_w[c] + we_b[c] + pos[l*NC + c];
        mean += x[c];
    }
    mean *= (1.f/NC);
    float var = 0.f;
#pragma unroll
    for (int c = 0; c < NC; c++){ float d = x[c] - mean; var += d*d; }
    var *= (1.f/NC);
    float inv = rsqrtf(var + 1e-5f);
#pragma unroll
    for (int c = 0; c < NC; c++) x[c] = (x[c] - mean)*inv*mn_g[c] + mn_b[c];

    // xs: static register index, wave-uniform predicate
#pragma unroll
    for (int c = 0; c < NC; c++)
        if ((c >> 2) == w) xs_s[c*NL + l] = x[c];

#pragma unroll
    for (int e4 = 0; e4 < 4; e4++){
        int e = w*4 + e4;
        float aq = bq[e], ak = bk[e], av = bv[e];
#pragma unroll
        for (int c = 0; c < NC; c++){
            float xv = x[c];
            aq += xv * wq[e*NC + c];
            ak += xv * wk[e*NC + c];
            av += xv * wv[e*NC + c];
        }
        qs_s[e*NL + l] = aq;
        ks_s[e*NL + l] = ak;
        vs_s[e*NL + l] = av;
    }
    __syncthreads();

    // ---- phase 2: attention; head h = w>>1, 4 lanes per row ----
    const int h   = w >> 1;
    const int sub = ((w & 1) << 6) | l;    // 0..127
    const int rl  = sub >> 2;              // local row 0..31
    const int q4  = sub & 3;               // m-quarter
    const int r   = half*32 + rl;          // global row
    const int m0  = q4*16;

    float q8[ND];
#pragma unroll
    for (int d = 0; d < ND; d++) q8[d] = qs_s[(h*ND + d)*NL + r];

    const float rs8 = 0.35355339059327373f;
    const float cw = conv_w[h], cb = conv_b[h];
    float srow[16];
    float mx = -1e30f;
#pragma unroll
    for (int mi = 0; mi < 16; mi++){
        int m = m0 + mi;
        float dot = 0.f;
#pragma unroll
        for (int d = 0; d < ND; d++)
            dot += q8[d] * ks_s[(h*ND + d)*NL + m];
        float v = dot*rs8 + bulk_s[rl*65 + m]*cw + cb;
        srow[mi] = v;
        mx = fmaxf(mx, v);
    }
    mx = fmaxf(mx, __shfl_xor(mx, 1));
    mx = fmaxf(mx, __shfl_xor(mx, 2));
    float sm = 0.f;
#pragma unroll
    for (int mi = 0; mi < 16; mi++){ srow[mi] = __expf(srow[mi] - mx); sm += srow[mi]; }
    sm += __shfl_xor(sm, 1);
    sm += __shfl_xor(sm, 2);
    float is = 1.f / sm;

    float o[ND];
#pragma unroll
    for (int d = 0; d < ND; d++) o[d] = 0.f;
#pragma unroll
    for (int mi = 0; mi < 16; mi++){
        float a = srow[mi] * is;
#pragma unroll
        for (int d = 0; d < ND; d++)
            o[d] += a * vs_s[(h*ND + d)*NL + m0 + mi];
    }
#pragma unroll
    for (int d = 0; d < ND; d++){
        o[d] += __shfl_xor(o[d], 1);
        o[d] += __shfl_xor(o[d], 2);
    }

    // gate: compute all 8 channels (static o[] index), quad-lane q4==c8>>1 writes
#pragma unroll
    for (int c8 = 0; c8 < ND; c8++){
        float g = gate_b[h*ND + c8];
#pragma unroll
        for (int d = 0; d < ND; d++) g += gate_w[(h*ND + c8)*ND + d] * o[d];
        float val = o[c8] * (1.f/(1.f + __expf(-g)));
        if ((c8 >> 1) == q4) ao_s[(h*ND + c8)*NL + r] = val;
    }
    __syncthreads();

    // ---- phase 3: out-proj (2 channels/thread) + residual + LN ----
    const int r3  = t & 31;            // local row
    const int rg  = half*32 + r3;      // global row
    const int cg  = t >> 5;            // channel group 0..15
    float vals[2];
    float psum = 0.f, psq = 0.f;
#pragma unroll
    for (int k = 0; k < 2; k++){
        int c = cg*2 + k;
        float a = bo[c];
#pragma unroll
        for (int e = 0; e < NC; e++) a += ao_s[e*NL + rg] * wo[c*NC + e];
        float val = xs_s[c*NL + rg] + a;
        vals[k] = val; psum += val; psq += val*val;
    }
    red1[r3*17 + cg] = psum;
    red2[r3*17 + cg] = psq;
    __syncthreads();
    if (t < 32){
        float sum = 0.f, ssq = 0.f;
#pragma unroll
        for (int g = 0; g < 16; g++){ sum += red1[t*17 + g]; ssq += red2[t*17 + g]; }
        float mn = sum * (1.f/NC);
        float vr = ssq * (1.f/NC) - mn*mn;
        mstat[t] = mn;
        istat[t] = rsqrtf(vr + 1e-5f);
    }
    __syncthreads();
    {
        float mn = mstat[r3], iv = istat[r3];
#pragma unroll
        for (int k = 0; k < 2; k++){
            int c = cg*2 + k;
            xpostT[((b*NS + s)*NC + c)*NL + rg] = (vals[k] - mn)*iv*an_g[c] + an_b[c];
        }
    }
}

// ---------------------------------------------------------------------------
// K23 v2 (unchanged): block=(b,it) -> 512 blocks, 256 threads, 48 KB LDS.
// pp_w staged to LDS in two 32 KB passes; mhat cooperative.
// ---------------------------------------------------------------------------
__global__ __launch_bounds__(256) void k23_pair(
    const float* __restrict__ xpostT, fp pp_w,
    fp pp_b, fp ada_g, fp ada_b, fp ada_alpha,
    float* __restrict__ out)
{
    __shared__ float ppws[8*NC*NC];   // 8192 floats, 32 KB (per pass)
    __shared__ float mh[NC*NL];       // 2048 floats
    __shared__ float u[NCP*4*NC];     // 2048 floats ([0..63] = invn early)

    const int b  = blockIdx.x >> 4;
    const int it = blockIdx.x & 15;
    const int t  = threadIdx.x;
    const int w  = t >> 6;
    const int j  = t & 63;

    const float* xb = xpostT + b*NS*NC*NL;
#pragma unroll
    for (int k = 0; k < 8; k++){
        int cj = k*256 + t;
        float v = xb[cj];
        v = fmaxf(v, xb[NC*NL + cj]);
        v = fmaxf(v, xb[2*NC*NL + cj]);
        v = fmaxf(v, xb[3*NC*NL + cj]);
        mh[cj] = v;
    }
    __syncthreads();

    if (t < NL){
        float sq = 0.f;
#pragma unroll
        for (int c = 0; c < NC; c++){ float v = mh[c*NL + t]; sq += v*v; }
        u[t] = 1.f / fmaxf(sqrtf(sq), 1e-3f);
    }
    {
        const float4* src = (const float4*)(pp_w);
        float4* dst = (float4*)ppws;
#pragma unroll
        for (int k = 0; k < 8; k++) dst[k*256 + t] = src[k*256 + t];
    }
    __syncthreads();

#pragma unroll
    for (int k = 0; k < 8; k++){
        int cj = k*256 + t;
        mh[cj] *= u[cj & 63];
    }
    __syncthreads();

    float md[NC];
#pragma unroll
    for (int c = 0; c < NC; c++) md[c] = mh[c*NL + j];

#pragma unroll
    for (int loop = 0; loop < 4; loop++){
        int idx = loop*256 + t;
        int d  = idx & 31;
        int ip = (idx >> 5) & 3;
        int pl = idx >> 7;
        int i  = it*4 + ip;
        float acc = 0.f;
#pragma unroll
        for (int c = 0; c < NC; c++)
            acc += mh[c*NL + i] * ppws[pl*1024 + c*32 + d];
        u[pl*128 + ip*32 + d] = acc;
    }
    __syncthreads();

    {
        const float4* src = (const float4*)(pp_w + 8*NC*NC);
        float4* dst = (float4*)ppws;
#pragma unroll
        for (int k = 0; k < 8; k++) dst[k*256 + t] = src[k*256 + t];
    }
    __syncthreads();

#pragma unroll
    for (int loop = 0; loop < 4; loop++){
        int idx = loop*256 + t;
        int d  = idx & 31;
        int ip = (idx >> 5) & 3;
        int pl = idx >> 7;
        int i  = it*4 + ip;
        float acc = 0.f;
#pragma unroll
        for (int c = 0; c < NC; c++)
            acc += mh[c*NL + i] * ppws[pl*1024 + c*32 + d];
        u[(8 + pl)*128 + ip*32 + d] = acc;
    }
    __syncthreads();

    float f[NCP];
#pragma unroll 1
    for (int p = 0; p < NCP; p++){
        float a = 0.f;
#pragma unroll
        for (int d = 0; d < NC; d++)
            a += u[p*128 + w*32 + d] * md[d];
        f[p] = a;
    }

    const float alpha = ada_alpha[0];
    float fsum = 0.f, fsq = 0.f;
#pragma unroll
    for (int p = 0; p < NCP; p++){
        float v = f[p] + pp_b[p];
        f[p] = v; fsum += v; fsq += v*v;
    }
    float fmean = fsum * (1.f/NCP);
    float fvar  = fsq * (1.f/NCP) - fmean*fmean;
    float finv  = rsqrtf(fvar + 1e-5f);
    const int i = it*4 + w;
#pragma unroll
    for (int p = 0; p < NCP; p++){
        float v = f[p] + alpha * ((f[p] - fmean)*finv*ada_g[p] + ada_b[p]);
        out[((b*NCP + p)*NL + i)*NL + j] = v / (1.f + __expf(-v));
    }
}

extern "C" void kernel_launch(void* const* d_in, const int* in_sizes, int n_in,
                              void* d_out, int out_size, void* d_ws, size_t ws_size,
                              hipStream_t stream)
{
    float* xpostT = (float*)d_ws;                    // 32*4*32*64 = 262144 f32

    k1_attn<<<NB*NS*2, 512, 0, stream>>>(
        (fp)d_in[0], (fp)d_in[1], (fp)d_in[2], (fp)d_in[3], (fp)d_in[4],
        (fp)d_in[5], (fp)d_in[6], (fp)d_in[7], (fp)d_in[8], (fp)d_in[9],
        (fp)d_in[10], (fp)d_in[11], (fp)d_in[12], (fp)d_in[13], (fp)d_in[14], (fp)d_in[15],
        (fp)d_in[16], (fp)d_in[17], (fp)d_in[18], (fp)d_in[19],
        (fp)d_in[20], (fp)d_in[21], (fp)d_in[22], (fp)d_in[23], xpostT);

    k23_pair<<<NB*16, 256, 0, stream>>>(
        xpostT, (fp)d_in[24], (fp)d_in[25], (fp)d_in[26], (fp)d_in[27], (fp)d_in[28],
        (float*)d_out);
}